// Round 11
// baseline (97.362 us; speedup 1.0000x reference)
//
#include <hip/hip_runtime.h>
#include <climits>

#define NPTS 1024
#define DIMD 64
#define KNN  16
#define HID  256
#define EMBH 64

typedef short short8 __attribute__((ext_vector_type(8)));
typedef float f32x4  __attribute__((ext_vector_type(4)));

__device__ __forceinline__ short f2bf(float x) {            // RNE fp32->bf16
    unsigned u = __float_as_uint(x);
    unsigned r = (u + 0x7fffu + ((u >> 16) & 1u)) >> 16;
    return (short)r;
}
__device__ __forceinline__ float bf2f(short s) {
    return __uint_as_float(((unsigned)(unsigned short)s) << 16);
}

// A-operand LDS layout (shorts): element (k, m) of A[16 m][K k]
#define AOFF(k, m) ((((k) >> 3) * 16 + (m)) * 8 + ((k) & 7))

// ws layout (shorts) — B-fragment bf16 planes
#define A1H 0
#define A2H 16384
#define WKH 32768
#define WVH 36864
#define P2H 40960

// ---------- prep: vectorized weight -> B-fragment bf16 conversion ----------
__global__ __launch_bounds__(256) void prep_weights(
    const float* __restrict__ A1, const float* __restrict__ A2,
    const float* __restrict__ Wk, const float* __restrict__ Wv,
    const float* __restrict__ P2, short* __restrict__ ws)
{
    int e = blockIdx.x * 256 + threadIdx.x;   // 0 .. 88*64-1
    if (e >= 88 * 64) return;
    int f = e >> 6, lane = e & 63;
    int q = (lane >> 4) & 3, nn = lane & 15;
    const float* src; int N, base, lf, cpt;
    if (f < 32)      { src = A1; N = 256; base = A1H; lf = f;      cpt = 2; }
    else if (f < 64) { src = A2; N = 64;  base = A2H; lf = f - 32; cpt = 8; }
    else if (f < 72) { src = Wk; N = 64;  base = WKH; lf = f - 64; cpt = 2; }
    else if (f < 80) { src = Wv; N = 64;  base = WVH; lf = f - 72; cpt = 2; }
    else             { src = P2; N = 64;  base = P2H; lf = f - 80; cpt = 2; }
    int T = lf / cpt, c = lf % cpt;
    int n  = T * 16 + nn;
    int k0 = c * 32 + q * 8;
    short8 v;
    #pragma unroll
    for (int j = 0; j < 8; j++) v[j] = f2bf(src[(k0 + j) * N + n]);
    *(short8*)(ws + base + lf * 512 + lane * 8) = v;
}

// ---------- main fused kernel: one block (256 thr) per point ----------
__global__ __launch_bounds__(256, 4) void ptl_fused(
    const float* __restrict__ x,  const float* __restrict__ pos,
    const float* __restrict__ Wq,
    const float* __restrict__ P1, const float* __restrict__ pb1,
    const float* __restrict__ pb2,
    const float* __restrict__ ab1, const float* __restrict__ ab2,
    const short* __restrict__ ws,
    float* __restrict__ out)
{
    __shared__ __align__(16) short a_xn_hi[16*64],  a_xn_lo[16*64];
    __shared__ __align__(16) short a_es_hi[16*64],  a_es_lo[16*64];
    __shared__ __align__(16) short a_h_hi [16*64],  a_h_lo [16*64];
    __shared__ __align__(16) short a_hd[2*16*256];   // hd_hi | hd_lo; aliased: 16x256 int hist / tie list
    __shared__ __align__(16) float s_vg[16*68];
    __shared__ __align__(16) float s_sim[16*68];
    __shared__ float s_q[DIMD];
    __shared__ int   s_idx[KNN];
    __shared__ int   s_cnt, s_cnt2, s_need;
    __shared__ unsigned s_pref;

    short* a_hd_hi = a_hd;
    short* a_hd_lo = a_hd + 16*256;

    const int i    = blockIdx.x;
    const int tid  = threadIdx.x;
    const int lane = tid & 63;
    const int w    = tid >> 6;        // wave id 0..3
    const int q4   = lane >> 4;       // quad
    const int col  = lane & 15;

    const float px = pos[i*3+0], py = pos[i*3+1], pz = pos[i*3+2];

    // ---- Phase 1: distance keys (non-fused fp32 = np's compare key, bit-monotone) ----
    unsigned ku[4];
    #pragma unroll
    for (int u = 0; u < 4; u++) {
        int j = tid + 256 * u;
        float dx = __fsub_rn(px, pos[j*3+0]);
        float dy = __fsub_rn(py, pos[j*3+1]);
        float dz = __fsub_rn(pz, pos[j*3+2]);
        float s  = __fadd_rn(__fadd_rn(__fmul_rn(dx,dx), __fmul_rn(dy,dy)), __fmul_rn(dz,dz));
        ku[u] = __float_as_uint(__fsqrt_rn(s));
    }

    // ---- Phase 2: exact MSB radix-select of 16 smallest keys ----
    // 16 per-quad sub-histograms (group g = w*4+q4) to cut same-bin LDS-atomic serialization.
    int* histI = (int*)a_hd;      // 16 x 256 ints = 16 KB (aliased, dead region)
    int* s_tie = (int*)(a_hd + 16*256);   // tie candidate indices (<=256), in hd_lo
    const int g = w * 4 + q4;
    if (tid == 0) { s_cnt = 0; s_cnt2 = 0; s_pref = 0u; s_need = KNN; }

    for (int r = 0; r < 4; r++) {
        const int shift = 24 - 8 * r;
        for (int t = tid; t < 16 * 256; t += 256) histI[t] = 0;
        __syncthreads();
        unsigned pref = s_pref;
        #pragma unroll
        for (int u = 0; u < 4; u++) {
            unsigned k = ku[u];
            bool match = true;
            if (r > 0) match = ((k >> (shift + 8)) == (pref >> (shift + 8)));
            if (match) atomicAdd(&histI[g * 256 + ((k >> shift) & 255)], 1);
        }
        __syncthreads();
        if (w == 0) {
            int b0 = lane * 4, cnt4[4], loc = 0;
            #pragma unroll
            for (int t = 0; t < 4; t++) {
                int s = 0;
                #pragma unroll
                for (int gg = 0; gg < 16; gg++) s += histI[gg * 256 + b0 + t];
                cnt4[t] = s; loc += s;
            }
            int incl = loc;
            #pragma unroll
            for (int off = 1; off < 64; off <<= 1) {
                int t = __shfl_up(incl, off);
                if (lane >= off) incl += t;
            }
            int excl = incl - loc;
            int need = s_need;
            unsigned long long mk = __ballot(incl >= need);
            int lstar = (int)__ffsll((long long)mk) - 1;
            if (lane == lstar) {
                int run = excl, t = 0;
                while (t < 3 && run + cnt4[t] < need) { run += cnt4[t]; t++; }
                s_pref = pref | ((unsigned)(b0 + t) << shift);
                s_need = need - run;
            }
        }
        __syncthreads();
    }
    const unsigned T = s_pref;
    const int needT  = s_need;     // #slots to fill with keys == T (>=1)

    // collect: all keys < T, then the needT smallest-index keys == T (np stable top_k set)
    #pragma unroll
    for (int u = 0; u < 4; u++) {
        unsigned k = ku[u];
        int j = tid + 256 * u;
        if (k < T)       { int p = atomicAdd(&s_cnt, 1);  s_idx[p] = j; }
        else if (k == T) { int p = atomicAdd(&s_cnt2, 1); if (p < 256) s_tie[p] = j; }
    }
    __syncthreads();

    if (w == 0) {
        int base = s_cnt;          // == KNN - needT
        int m = s_cnt2;
        if (m == needT) {
            for (int t = lane; t < m; t += 64) s_idx[base + t] = s_tie[t];
        } else {
            int cand[4];
            #pragma unroll
            for (int t = 0; t < 4; t++) {
                int e = lane + 64 * t;
                cand[t] = (e < m && e < 256) ? s_tie[e] : INT_MAX;
            }
            for (int sel = 0; sel < needT; sel++) {
                int mv = cand[0];
                #pragma unroll
                for (int t = 1; t < 4; t++) mv = min(mv, cand[t]);
                #pragma unroll
                for (int off = 32; off > 0; off >>= 1) mv = min(mv, __shfl_xor(mv, off));
                #pragma unroll
                for (int t = 0; t < 4; t++) if (cand[t] == mv) cand[t] = INT_MAX;
                if (lane == 0) s_idx[base + sel] = mv;
            }
        }
    } else if (w == 1) {
        int d = lane;
        const float4* xr = (const float4*)(x + i * DIMD);
        float aq = 0.f;
        #pragma unroll
        for (int cb = 0; cb < DIMD / 4; cb++) {
            float4 xv = xr[cb];
            const float* wq = Wq + (cb*4) * DIMD + d;
            aq = fmaf(xv.x, wq[0*DIMD], aq); aq = fmaf(xv.y, wq[1*DIMD], aq);
            aq = fmaf(xv.z, wq[2*DIMD], aq); aq = fmaf(xv.w, wq[3*DIMD], aq);
        }
        s_q[d] = aq;
    }
    __syncthreads();

    // ---- Phase 3: gather xn + emb1, write as A-frag bf16 hi/lo ----
    #pragma unroll
    for (int u = 0; u < 4; u++) {
        int t = tid + 256 * u;          // 0..1023
        int kk = t >> 6, c = t & 63;
        int j = s_idx[kk];
        int ao = AOFF(c, kk);
        float xv = x[j * DIMD + c];
        short xh = f2bf(xv);
        a_xn_hi[ao] = xh;
        a_xn_lo[ao] = f2bf(xv - bf2f(xh));
        float dx = px - pos[j*3+0];
        float dy = py - pos[j*3+1];
        float dz = pz - pos[j*3+2];
        float a = pb1[c];
        a = fmaf(dx, P1[0*EMBH+c], a);
        a = fmaf(dy, P1[1*EMBH+c], a);
        a = fmaf(dz, P1[2*EMBH+c], a);
        a = fmaxf(a, 0.0f);
        short eh = f2bf(a);
        a_es_hi[ao] = eh;
        a_es_lo[ao] = f2bf(a - bf2f(eh));
    }
    __syncthreads();

    const short8* wsv  = (const short8*)ws;
    const short8* xnh  = (const short8*)a_xn_hi;
    const short8* xnl  = (const short8*)a_xn_lo;
    const short8* esh  = (const short8*)a_es_hi;
    const short8* esl  = (const short8*)a_es_lo;
    const short8* hhv  = (const short8*)a_h_hi;
    const short8* hlv  = (const short8*)a_h_lo;
    const short8* hdh  = (const short8*)a_hd_hi;
    const short8* hdl  = (const short8*)a_hd_lo;

    auto bfrag = [&](int short_base, int f) -> short8 {
        return wsv[(short_base >> 3) + f * 64 + lane];
    };

    // ---- Group 1 MFMA: kn = xn@Wk, vn = xn@Wv, rpe = emb1@P2 (each 16x64, K=64) ----
    {
        f32x4 acck = {0,0,0,0}, accv = {0,0,0,0}, accr = {0,0,0,0};
        #pragma unroll
        for (int c = 0; c < 2; c++) {
            int av = (4*c + q4) * 16 + col;
            short8 xh = xnh[av], xl = xnl[av];
            int f = w * 2 + c;
            short8 bk = bfrag(WKH, f);
            short8 bv = bfrag(WVH, f);
            acck = __builtin_amdgcn_mfma_f32_16x16x32_bf16(xh, bk, acck, 0,0,0);
            acck = __builtin_amdgcn_mfma_f32_16x16x32_bf16(xl, bk, acck, 0,0,0);
            accv = __builtin_amdgcn_mfma_f32_16x16x32_bf16(xh, bv, accv, 0,0,0);
            accv = __builtin_amdgcn_mfma_f32_16x16x32_bf16(xl, bv, accv, 0,0,0);
        }
        #pragma unroll
        for (int c = 0; c < 2; c++) {
            int av = (4*c + q4) * 16 + col;
            short8 eh = esh[av], el = esl[av];
            short8 bp = bfrag(P2H, w * 2 + c);
            accr = __builtin_amdgcn_mfma_f32_16x16x32_bf16(eh, bp, accr, 0,0,0);
            accr = __builtin_amdgcn_mfma_f32_16x16x32_bf16(el, bp, accr, 0,0,0);
        }
        int d = w * 16 + col;
        float qd = s_q[d], pb = pb2[d];
        #pragma unroll
        for (int r = 0; r < 4; r++) {
            int s = q4 * 4 + r;
            float rpe = accr[r] + pb;
            float hv  = qd - acck[r] + rpe;
            s_vg[s * 68 + d] = accv[r] + rpe;
            int ao = AOFF(d, s);
            short hh = f2bf(hv);
            a_h_hi[ao] = hh;
            a_h_lo[ao] = f2bf(hv - bf2f(hh));
        }
    }
    __syncthreads();

    // ---- Step C MFMA: hidden = relu(h @ A1 + ab1), 16x256, K=64 ----
    {
        short8 hh[2], hl[2];
        #pragma unroll
        for (int c = 0; c < 2; c++) {
            int av = (4*c + q4) * 16 + col;
            hh[c] = hhv[av]; hl[c] = hlv[av];
        }
        #pragma unroll
        for (int t = 0; t < 4; t++) {
            int T4 = w * 4 + t;
            f32x4 acc = {0,0,0,0};
            #pragma unroll
            for (int c = 0; c < 2; c++) {
                short8 bh = bfrag(A1H, T4 * 2 + c);
                acc = __builtin_amdgcn_mfma_f32_16x16x32_bf16(hh[c], bh, acc, 0,0,0);
                acc = __builtin_amdgcn_mfma_f32_16x16x32_bf16(hl[c], bh, acc, 0,0,0);
            }
            int n = T4 * 16 + col;
            float bias = ab1[n];
            #pragma unroll
            for (int r = 0; r < 4; r++) {
                float val = fmaxf(acc[r] + bias, 0.0f);
                int ao = AOFF(n, q4 * 4 + r);
                short vh = f2bf(val);
                a_hd_hi[ao] = vh;
                a_hd_lo[ao] = f2bf(val - bf2f(vh));
            }
        }
    }
    __syncthreads();

    // ---- Step D MFMA: sim = hidden @ A2 + ab2, 16x64, K=256 (dual acc chains) ----
    {
        f32x4 acc0 = {0,0,0,0}, acc1 = {0,0,0,0};
        #pragma unroll
        for (int c = 0; c < 8; c += 2) {
            {
                int av = (4*c + q4) * 16 + col;
                short8 ah = hdh[av], al = hdl[av];
                short8 bh = bfrag(A2H, w * 8 + c);
                acc0 = __builtin_amdgcn_mfma_f32_16x16x32_bf16(ah, bh, acc0, 0,0,0);
                acc0 = __builtin_amdgcn_mfma_f32_16x16x32_bf16(al, bh, acc0, 0,0,0);
            }
            {
                int av = (4*(c+1) + q4) * 16 + col;
                short8 ah = hdh[av], al = hdl[av];
                short8 bh = bfrag(A2H, w * 8 + c + 1);
                acc1 = __builtin_amdgcn_mfma_f32_16x16x32_bf16(ah, bh, acc1, 0,0,0);
                acc1 = __builtin_amdgcn_mfma_f32_16x16x32_bf16(al, bh, acc1, 0,0,0);
            }
        }
        int n = w * 16 + col;
        float bias = ab2[n];
        #pragma unroll
        for (int r = 0; r < 4; r++)
            s_sim[(q4 * 4 + r) * 68 + n] = acc0[r] + acc1[r] + bias;
    }
    __syncthreads();

    // ---- Step E: softmax over neighbors per dim, weighted sum of vg ----
    if (tid < DIMD) {
        int d = tid;
        float mx = -3.0e38f;
        #pragma unroll
        for (int kk = 0; kk < KNN; kk++) mx = fmaxf(mx, s_sim[kk * 68 + d]);
        float den = 0.0f, num = 0.0f;
        #pragma unroll
        for (int kk = 0; kk < KNN; kk++) {
            float e = expf(s_sim[kk * 68 + d] - mx);
            den += e;
            num = fmaf(e, s_vg[kk * 68 + d], num);
        }
        out[i * DIMD + d] = num / den;
    }
}

extern "C" void kernel_launch(void* const* d_in, const int* in_sizes, int n_in,
                              void* d_out, int out_size, void* d_ws, size_t ws_size,
                              hipStream_t stream) {
    const float* x   = (const float*)d_in[0];
    const float* pos = (const float*)d_in[1];
    const float* Wq  = (const float*)d_in[2];
    const float* Wk  = (const float*)d_in[3];
    const float* Wv  = (const float*)d_in[4];
    const float* P1  = (const float*)d_in[5];
    const float* pb1 = (const float*)d_in[6];
    const float* P2  = (const float*)d_in[7];
    const float* pb2 = (const float*)d_in[8];
    const float* A1  = (const float*)d_in[9];
    const float* ab1 = (const float*)d_in[10];
    const float* A2  = (const float*)d_in[11];
    const float* ab2 = (const float*)d_in[12];
    float* out = (float*)d_out;
    short* ws  = (short*)d_ws;

    prep_weights<<<22, 256, 0, stream>>>(A1, A2, Wk, Wv, P2, ws);
    ptl_fused<<<NPTS, 256, 0, stream>>>(x, pos, Wq, P1, pb1, pb2, ab1, ab2, ws, out);
}

// Round 12
// 93.396 us; speedup vs baseline: 1.0425x; 1.0425x over previous
//
#include <hip/hip_runtime.h>
#include <climits>

#define NPTS 1024
#define DIMD 64
#define KNN  16
#define HID  256
#define EMBH 64

typedef short short8 __attribute__((ext_vector_type(8)));
typedef float f32x4  __attribute__((ext_vector_type(4)));

__device__ __forceinline__ short f2bf(float x) {            // RNE fp32->bf16
    unsigned u = __float_as_uint(x);
    unsigned r = (u + 0x7fffu + ((u >> 16) & 1u)) >> 16;
    return (short)r;
}
__device__ __forceinline__ float bf2f(short s) {
    return __uint_as_float(((unsigned)(unsigned short)s) << 16);
}

// A-operand LDS layout (shorts): element (k, m) of A[16 m][K k]
#define AOFF(k, m) ((((k) >> 3) * 16 + (m)) * 8 + ((k) & 7))

// ws layout (shorts) — B-fragment bf16 planes
#define A1H 0
#define A2H 16384
#define WKH 32768
#define WVH 36864
#define P2H 40960

// ---------- prep: vectorized weight -> B-fragment bf16 conversion ----------
__global__ __launch_bounds__(256) void prep_weights(
    const float* __restrict__ A1, const float* __restrict__ A2,
    const float* __restrict__ Wk, const float* __restrict__ Wv,
    const float* __restrict__ P2, short* __restrict__ ws)
{
    int e = blockIdx.x * 256 + threadIdx.x;   // 0 .. 88*64-1
    if (e >= 88 * 64) return;
    int f = e >> 6, lane = e & 63;
    int q = (lane >> 4) & 3, nn = lane & 15;
    const float* src; int N, base, lf, cpt;
    if (f < 32)      { src = A1; N = 256; base = A1H; lf = f;      cpt = 2; }
    else if (f < 64) { src = A2; N = 64;  base = A2H; lf = f - 32; cpt = 8; }
    else if (f < 72) { src = Wk; N = 64;  base = WKH; lf = f - 64; cpt = 2; }
    else if (f < 80) { src = Wv; N = 64;  base = WVH; lf = f - 72; cpt = 2; }
    else             { src = P2; N = 64;  base = P2H; lf = f - 80; cpt = 2; }
    int T = lf / cpt, c = lf % cpt;
    int n  = T * 16 + nn;
    int k0 = c * 32 + q * 8;
    short8 v;
    #pragma unroll
    for (int j = 0; j < 8; j++) v[j] = f2bf(src[(k0 + j) * N + n]);
    *(short8*)(ws + base + lf * 512 + lane * 8) = v;
}

// ---------- main fused kernel: one block (256 thr) per point ----------
__global__ __launch_bounds__(256, 4) void ptl_fused(
    const float* __restrict__ x,  const float* __restrict__ pos,
    const float* __restrict__ Wq,
    const float* __restrict__ P1, const float* __restrict__ pb1,
    const float* __restrict__ pb2,
    const float* __restrict__ ab1, const float* __restrict__ ab2,
    const short* __restrict__ ws,
    float* __restrict__ out)
{
    __shared__ __align__(16) short a_xn_hi[16*64],  a_xn_lo[16*64];
    __shared__ __align__(16) short a_es_hi[16*64],  a_es_lo[16*64];
    __shared__ __align__(16) short a_h_hi [16*64],  a_h_lo [16*64];
    __shared__ __align__(16) short a_hd_hi[16*256], a_hd_lo[16*256]; // aliased: dbuf hist / ties
    __shared__ __align__(16) float s_vg[16*68];
    __shared__ __align__(16) float s_sim[16*68];
    __shared__ float s_q[DIMD];
    __shared__ int   s_idx[KNN];
    __shared__ int   s_cnt, s_cnt2, s_need;
    __shared__ unsigned s_pref;

    const int i    = blockIdx.x;
    const int tid  = threadIdx.x;
    const int lane = tid & 63;
    const int w    = tid >> 6;        // wave id 0..3
    const int q4   = lane >> 4;       // quad
    const int col  = lane & 15;

    const float px = pos[i*3+0], py = pos[i*3+1], pz = pos[i*3+2];

    // ---- Phase 1: distance keys (non-fused fp32 = np's compare key, bit-monotone) ----
    unsigned ku[4];
    #pragma unroll
    for (int u = 0; u < 4; u++) {
        int j = tid + 256 * u;
        float dx = __fsub_rn(px, pos[j*3+0]);
        float dy = __fsub_rn(py, pos[j*3+1]);
        float dz = __fsub_rn(pz, pos[j*3+2]);
        float s  = __fadd_rn(__fadd_rn(__fmul_rn(dx,dx), __fmul_rn(dy,dy)), __fmul_rn(dz,dz));
        ku[u] = __float_as_uint(__fsqrt_rn(s));
    }

    // ---- Phase 2: exact MSB radix-select, double-buffered 4x257 histograms ----
    // buffers live in the dead a_hd region (2 x 1028 ints = 8224 B each, 16 KB available)
    int* histA = (int*)a_hd_hi;               // buffer 0: 4 waves x 257 ints
    int* histB = (int*)a_hd_lo;               // buffer 1
    int* s_tie = ((int*)a_hd_lo) + 1100;      // tie candidates (<=256), clear of histB
    if (tid == 0) { s_cnt = 0; s_cnt2 = 0; s_pref = 0u; s_need = KNN; }
    // zero both buffers once
    for (int t = tid; t < 1028; t += 256) { histA[t] = 0; histB[t] = 0; }
    __syncthreads();

    for (int r = 0; r < 4; r++) {
        const int shift = 24 - 8 * r;
        int* hist = (r & 1) ? histB : histA;
        unsigned pref = s_pref;
        #pragma unroll
        for (int u = 0; u < 4; u++) {
            unsigned k = ku[u];
            bool match = true;
            if (r > 0) match = ((k >> (shift + 8)) == (pref >> (shift + 8)));
            if (match) atomicAdd(&hist[w * 257 + ((k >> shift) & 255)], 1);
        }
        __syncthreads();
        if (w == 0) {   // wave 0 scans this round's buffer
            int b0 = lane * 4, cnt4[4], loc = 0;
            #pragma unroll
            for (int t = 0; t < 4; t++) {
                int s = 0;
                #pragma unroll
                for (int ww = 0; ww < 4; ww++) s += hist[ww * 257 + b0 + t];
                cnt4[t] = s; loc += s;
            }
            int incl = loc;
            #pragma unroll
            for (int off = 1; off < 64; off <<= 1) {
                int t = __shfl_up(incl, off);
                if (lane >= off) incl += t;
            }
            int excl = incl - loc;
            int need = s_need;
            unsigned long long mk = __ballot(incl >= need);
            int lstar = (int)__ffsll((long long)mk) - 1;
            if (lane == lstar) {
                int run = excl, t = 0;
                while (t < 3 && run + cnt4[t] < need) { run += cnt4[t]; t++; }
                s_pref = pref | ((unsigned)(b0 + t) << shift);
                s_need = need - run;
            }
        } else if (r < 3) {   // waves 1..3 zero the NEXT round's buffer meanwhile
            int* nxt = (r & 1) ? histA : histB;
            for (int t = tid - 64; t < 1028; t += 192) nxt[t] = 0;
        }
        __syncthreads();
    }
    const unsigned T = s_pref;
    const int needT  = s_need;     // #slots to fill with keys == T (>=1)

    // collect: all keys < T, then the needT smallest-index keys == T (np stable top_k set)
    #pragma unroll
    for (int u = 0; u < 4; u++) {
        unsigned k = ku[u];
        int j = tid + 256 * u;
        if (k < T)       { int p = atomicAdd(&s_cnt, 1);  s_idx[p] = j; }
        else if (k == T) { int p = atomicAdd(&s_cnt2, 1); if (p < 256) s_tie[p] = j; }
    }
    __syncthreads();

    if (w == 0) {
        int base = s_cnt;          // == KNN - needT
        int m = s_cnt2;
        if (m == needT) {
            for (int t = lane; t < m; t += 64) s_idx[base + t] = s_tie[t];
        } else {
            int cand[4];
            #pragma unroll
            for (int t = 0; t < 4; t++) {
                int e = lane + 64 * t;
                cand[t] = (e < m && e < 256) ? s_tie[e] : INT_MAX;
            }
            for (int sel = 0; sel < needT; sel++) {
                int mv = cand[0];
                #pragma unroll
                for (int t = 1; t < 4; t++) mv = min(mv, cand[t]);
                #pragma unroll
                for (int off = 32; off > 0; off >>= 1) mv = min(mv, __shfl_xor(mv, off));
                #pragma unroll
                for (int t = 0; t < 4; t++) if (cand[t] == mv) cand[t] = INT_MAX;
                if (lane == 0) s_idx[base + sel] = mv;
            }
        }
    } else if (w == 1) {
        int d = lane;
        const float4* xr = (const float4*)(x + i * DIMD);
        float aq = 0.f;
        #pragma unroll
        for (int cb = 0; cb < DIMD / 4; cb++) {
            float4 xv = xr[cb];
            const float* wq = Wq + (cb*4) * DIMD + d;
            aq = fmaf(xv.x, wq[0*DIMD], aq); aq = fmaf(xv.y, wq[1*DIMD], aq);
            aq = fmaf(xv.z, wq[2*DIMD], aq); aq = fmaf(xv.w, wq[3*DIMD], aq);
        }
        s_q[d] = aq;
    }
    __syncthreads();

    // ---- Phase 3: gather xn + emb1, write as A-frag bf16 hi/lo ----
    #pragma unroll
    for (int u = 0; u < 4; u++) {
        int t = tid + 256 * u;          // 0..1023
        int kk = t >> 6, c = t & 63;
        int j = s_idx[kk];
        int ao = AOFF(c, kk);
        float xv = x[j * DIMD + c];
        short xh = f2bf(xv);
        a_xn_hi[ao] = xh;
        a_xn_lo[ao] = f2bf(xv - bf2f(xh));
        float dx = px - pos[j*3+0];
        float dy = py - pos[j*3+1];
        float dz = pz - pos[j*3+2];
        float a = pb1[c];
        a = fmaf(dx, P1[0*EMBH+c], a);
        a = fmaf(dy, P1[1*EMBH+c], a);
        a = fmaf(dz, P1[2*EMBH+c], a);
        a = fmaxf(a, 0.0f);
        short eh = f2bf(a);
        a_es_hi[ao] = eh;
        a_es_lo[ao] = f2bf(a - bf2f(eh));
    }
    __syncthreads();

    const short8* wsv  = (const short8*)ws;
    const short8* xnh  = (const short8*)a_xn_hi;
    const short8* xnl  = (const short8*)a_xn_lo;
    const short8* esh  = (const short8*)a_es_hi;
    const short8* esl  = (const short8*)a_es_lo;
    const short8* hhv  = (const short8*)a_h_hi;
    const short8* hlv  = (const short8*)a_h_lo;
    const short8* hdh  = (const short8*)a_hd_hi;
    const short8* hdl  = (const short8*)a_hd_lo;

    auto bfrag = [&](int short_base, int f) -> short8 {
        return wsv[(short_base >> 3) + f * 64 + lane];
    };

    // ---- Group 1 MFMA: kn = xn@Wk, vn = xn@Wv, rpe = emb1@P2 (each 16x64, K=64) ----
    {
        f32x4 acck = {0,0,0,0}, accv = {0,0,0,0}, accr = {0,0,0,0};
        #pragma unroll
        for (int c = 0; c < 2; c++) {
            int av = (4*c + q4) * 16 + col;
            short8 xh = xnh[av], xl = xnl[av];
            int f = w * 2 + c;
            short8 bk = bfrag(WKH, f);
            short8 bv = bfrag(WVH, f);
            acck = __builtin_amdgcn_mfma_f32_16x16x32_bf16(xh, bk, acck, 0,0,0);
            acck = __builtin_amdgcn_mfma_f32_16x16x32_bf16(xl, bk, acck, 0,0,0);
            accv = __builtin_amdgcn_mfma_f32_16x16x32_bf16(xh, bv, accv, 0,0,0);
            accv = __builtin_amdgcn_mfma_f32_16x16x32_bf16(xl, bv, accv, 0,0,0);
        }
        #pragma unroll
        for (int c = 0; c < 2; c++) {
            int av = (4*c + q4) * 16 + col;
            short8 eh = esh[av], el = esl[av];
            short8 bp = bfrag(P2H, w * 2 + c);
            accr = __builtin_amdgcn_mfma_f32_16x16x32_bf16(eh, bp, accr, 0,0,0);
            accr = __builtin_amdgcn_mfma_f32_16x16x32_bf16(el, bp, accr, 0,0,0);
        }
        int d = w * 16 + col;
        float qd = s_q[d], pb = pb2[d];
        #pragma unroll
        for (int r = 0; r < 4; r++) {
            int s = q4 * 4 + r;
            float rpe = accr[r] + pb;
            float hv  = qd - acck[r] + rpe;
            s_vg[s * 68 + d] = accv[r] + rpe;
            int ao = AOFF(d, s);
            short hh = f2bf(hv);
            a_h_hi[ao] = hh;
            a_h_lo[ao] = f2bf(hv - bf2f(hh));
        }
    }
    __syncthreads();

    // ---- Step C MFMA: hidden = relu(h @ A1 + ab1), 16x256, K=64 ----
    {
        short8 hh[2], hl[2];
        #pragma unroll
        for (int c = 0; c < 2; c++) {
            int av = (4*c + q4) * 16 + col;
            hh[c] = hhv[av]; hl[c] = hlv[av];
        }
        #pragma unroll
        for (int t = 0; t < 4; t++) {
            int T4 = w * 4 + t;
            f32x4 acc = {0,0,0,0};
            #pragma unroll
            for (int c = 0; c < 2; c++) {
                short8 bh = bfrag(A1H, T4 * 2 + c);
                acc = __builtin_amdgcn_mfma_f32_16x16x32_bf16(hh[c], bh, acc, 0,0,0);
                acc = __builtin_amdgcn_mfma_f32_16x16x32_bf16(hl[c], bh, acc, 0,0,0);
            }
            int n = T4 * 16 + col;
            float bias = ab1[n];
            #pragma unroll
            for (int r = 0; r < 4; r++) {
                float val = fmaxf(acc[r] + bias, 0.0f);
                int ao = AOFF(n, q4 * 4 + r);
                short vh = f2bf(val);
                a_hd_hi[ao] = vh;
                a_hd_lo[ao] = f2bf(val - bf2f(vh));
            }
        }
    }
    __syncthreads();

    // ---- Step D MFMA: sim = hidden @ A2 + ab2, 16x64, K=256 (dual acc chains) ----
    {
        f32x4 acc0 = {0,0,0,0}, acc1 = {0,0,0,0};
        #pragma unroll
        for (int c = 0; c < 8; c += 2) {
            {
                int av = (4*c + q4) * 16 + col;
                short8 ah = hdh[av], al = hdl[av];
                short8 bh = bfrag(A2H, w * 8 + c);
                acc0 = __builtin_amdgcn_mfma_f32_16x16x32_bf16(ah, bh, acc0, 0,0,0);
                acc0 = __builtin_amdgcn_mfma_f32_16x16x32_bf16(al, bh, acc0, 0,0,0);
            }
            {
                int av = (4*(c+1) + q4) * 16 + col;
                short8 ah = hdh[av], al = hdl[av];
                short8 bh = bfrag(A2H, w * 8 + c + 1);
                acc1 = __builtin_amdgcn_mfma_f32_16x16x32_bf16(ah, bh, acc1, 0,0,0);
                acc1 = __builtin_amdgcn_mfma_f32_16x16x32_bf16(al, bh, acc1, 0,0,0);
            }
        }
        int n = w * 16 + col;
        float bias = ab2[n];
        #pragma unroll
        for (int r = 0; r < 4; r++)
            s_sim[(q4 * 4 + r) * 68 + n] = acc0[r] + acc1[r] + bias;
    }
    __syncthreads();

    // ---- Step E: softmax over neighbors per dim, weighted sum of vg ----
    if (tid < DIMD) {
        int d = tid;
        float mx = -3.0e38f;
        #pragma unroll
        for (int kk = 0; kk < KNN; kk++) mx = fmaxf(mx, s_sim[kk * 68 + d]);
        float den = 0.0f, num = 0.0f;
        #pragma unroll
        for (int kk = 0; kk < KNN; kk++) {
            float e = expf(s_sim[kk * 68 + d] - mx);
            den += e;
            num = fmaf(e, s_vg[kk * 68 + d], num);
        }
        out[i * DIMD + d] = num / den;
    }
}

extern "C" void kernel_launch(void* const* d_in, const int* in_sizes, int n_in,
                              void* d_out, int out_size, void* d_ws, size_t ws_size,
                              hipStream_t stream) {
    const float* x   = (const float*)d_in[0];
    const float* pos = (const float*)d_in[1];
    const float* Wq  = (const float*)d_in[2];
    const float* Wk  = (const float*)d_in[3];
    const float* Wv  = (const float*)d_in[4];
    const float* P1  = (const float*)d_in[5];
    const float* pb1 = (const float*)d_in[6];
    const float* P2  = (const float*)d_in[7];
    const float* pb2 = (const float*)d_in[8];
    const float* A1  = (const float*)d_in[9];
    const float* ab1 = (const float*)d_in[10];
    const float* A2  = (const float*)d_in[11];
    const float* ab2 = (const float*)d_in[12];
    float* out = (float*)d_out;
    short* ws  = (short*)d_ws;

    prep_weights<<<22, 256, 0, stream>>>(A1, A2, Wk, Wv, P2, ws);
    ptl_fused<<<NPTS, 256, 0, stream>>>(x, pos, Wq, P1, pb1, pb2, ab1, ab2, ws, out);
}